// Round 9
// baseline (27.021 us; speedup 1.0000x reference)
//
#include <hip/hip_runtime.h>

#define EPS 1e-8f

// x (32,1,96,96,96) f32, mask (1,1,96,96,96) i32, weight (2,1,96,96,96) f32,
// bias (2,) f32 -> out (32,2) f32.
constexpr int N4    = 221184;         // 96^3 / 4 float4 elements
constexpr int TPB   = 512;            // 8 waves/block
constexpr int BPW   = 4;              // batches per wave (8*4 = 32)
constexpr int NBLK3 = 1152;           // 1152*64*3 == N4 exactly: 3 uniform steps
constexpr int STR3  = NBLK3 * 64;     // 73728

// One pipeline stage: all 7 vector loads for one index step (BPW=4).
struct Stage {
    int4   mi;
    float4 w0, w1;
    float4 xv[BPW];
};

__device__ __forceinline__ void load_stage(Stage& s,
        const float4* __restrict__ x, const int4* __restrict__ mask,
        const float4* __restrict__ w, int i4, int b0)
{
    s.mi = mask[i4];
    s.w0 = w[i4];
    s.w1 = w[N4 + i4];
#pragma unroll
    for (int bb = 0; bb < BPW; ++bb)
        s.xv[bb] = x[(size_t)(b0 + bb) * N4 + i4];
}

__device__ __forceinline__ void compute_stage(const Stage& s, float (&acc)[BPW][2])
{
    const float m0 = s.mi.x ? 1.f : 0.f;
    const float m1 = s.mi.y ? 1.f : 0.f;
    const float m2 = s.mi.z ? 1.f : 0.f;
    const float m3 = s.mi.w ? 1.f : 0.f;
    const float wm0x = s.w0.x * m0, wm0y = s.w0.y * m1, wm0z = s.w0.z * m2, wm0w = s.w0.w * m3;
    const float wm1x = s.w1.x * m0, wm1y = s.w1.y * m1, wm1z = s.w1.z * m2, wm1w = s.w1.w * m3;
#pragma unroll
    for (int bb = 0; bb < BPW; ++bb) {
        const float4 xv = s.xv[bb];
        const float g0 = (fabsf(xv.x) > EPS) ? xv.x : 0.f;
        const float g1 = (fabsf(xv.y) > EPS) ? xv.y : 0.f;
        const float g2 = (fabsf(xv.z) > EPS) ? xv.z : 0.f;
        const float g3 = (fabsf(xv.w) > EPS) ? xv.w : 0.f;
        float a0 = acc[bb][0], a1 = acc[bb][1];
        a0 = fmaf(g0, wm0x, a0); a0 = fmaf(g1, wm0y, a0);
        a0 = fmaf(g2, wm0z, a0); a0 = fmaf(g3, wm0w, a0);
        a1 = fmaf(g0, wm1x, a1); a1 = fmaf(g1, wm1y, a1);
        a1 = fmaf(g2, wm1z, a1); a1 = fmaf(g3, wm1w, a1);
        acc[bb][0] = a0; acc[bb][1] = a1;
    }
}

__device__ __forceinline__ void reduce_and_store(
        float (&acc)[BPW][2], int lane, int b0, int bid, int nblk,
        float* __restrict__ partials)
{
#pragma unroll
    for (int bb = 0; bb < BPW; ++bb) {
#pragma unroll
        for (int c = 0; c < 2; ++c) {
            float v = acc[bb][c];
            v += __shfl_xor(v, 32, 64);
            v += __shfl_xor(v, 16, 64);
            v += __shfl_xor(v,  8, 64);
            v += __shfl_xor(v,  4, 64);
            v += __shfl_xor(v,  2, 64);
            v += __shfl_xor(v,  1, 64);
            acc[bb][c] = v;
        }
    }
    if (lane == 0) {
#pragma unroll
        for (int bb = 0; bb < BPW; ++bb) {
            partials[(size_t)((b0 + bb) * 2 + 0) * nblk + bid] = acc[bb][0];
            partials[(size_t)((b0 + bb) * 2 + 1) * nblk + bid] = acc[bb][1];
        }
    }
}

// Primary hot kernel. Grid MUST be exactly NBLK3 blocks of 512 threads.
// Uniform 3 steps/lane. R9 change: FULL-DEPTH pipeline — all 3 stages'
// loads (33 per lane) issued before any compute. Per-CU in-flight bytes
// ~2x R8 (8.4 KB vs 4.2 KB; latency window needs ~9.2 KB). Compiler emits
// counted vmcnt waits per compute_stage. NO min-waves clause (R5/R7: VGPR
// caps and fat epilogues destroy MLP — keep this kernel minimal).
__global__ __launch_bounds__(TPB) void partial_static3(
    const float4* __restrict__ x, const int4* __restrict__ mask,
    const float4* __restrict__ w, float* __restrict__ partials)
{
    const int tid  = threadIdx.x;
    const int wave = tid >> 6;
    const int lane = tid & 63;
    const int b0   = wave * BPW;
    const int bid  = blockIdx.x;
    const int i4   = bid * 64 + lane;          // [0, 73728)

    float acc[BPW][2];
#pragma unroll
    for (int bb = 0; bb < BPW; ++bb) { acc[bb][0] = 0.f; acc[bb][1] = 0.f; }

    Stage s0, s1, s2;
    load_stage(s0, x, mask, w, i4,            b0);
    load_stage(s1, x, mask, w, i4 + STR3,     b0);
    load_stage(s2, x, mask, w, i4 + 2 * STR3, b0);
    compute_stage(s0, acc);
    compute_stage(s1, acc);
    compute_stage(s2, acc);

    reduce_and_store(acc, lane, b0, bid, NBLK3, partials);
}

// Last-resort generic grid-stride partial (tiny ws).
__global__ __launch_bounds__(256) void partial_generic(
    const float4* __restrict__ x, const int4* __restrict__ mask,
    const float4* __restrict__ w, float* __restrict__ partials)
{
    const int tid  = threadIdx.x;
    const int wave = tid >> 6;
    const int lane = tid & 63;
    const int b0   = wave * 8;

    float acc[8][2];
#pragma unroll
    for (int bb = 0; bb < 8; ++bb) { acc[bb][0] = 0.f; acc[bb][1] = 0.f; }

    const int stride = gridDim.x * 64;
    for (int i4 = blockIdx.x * 64 + lane; i4 < N4; i4 += stride) {
        const int4   mi = mask[i4];
        const float4 w0 = w[i4];
        const float4 w1 = w[N4 + i4];
        const float m0 = mi.x ? 1.f : 0.f;
        const float m1 = mi.y ? 1.f : 0.f;
        const float m2 = mi.z ? 1.f : 0.f;
        const float m3 = mi.w ? 1.f : 0.f;
        const float wm0x = w0.x * m0, wm0y = w0.y * m1, wm0z = w0.z * m2, wm0w = w0.w * m3;
        const float wm1x = w1.x * m0, wm1y = w1.y * m1, wm1z = w1.z * m2, wm1w = w1.w * m3;
#pragma unroll
        for (int bb = 0; bb < 8; ++bb) {
            const float4 xv = x[(size_t)(b0 + bb) * N4 + i4];
            const float g0 = (fabsf(xv.x) > EPS) ? xv.x : 0.f;
            const float g1 = (fabsf(xv.y) > EPS) ? xv.y : 0.f;
            const float g2 = (fabsf(xv.z) > EPS) ? xv.z : 0.f;
            const float g3 = (fabsf(xv.w) > EPS) ? xv.w : 0.f;
            float a0 = acc[bb][0], a1 = acc[bb][1];
            a0 = fmaf(g0, wm0x, a0); a0 = fmaf(g1, wm0y, a0);
            a0 = fmaf(g2, wm0z, a0); a0 = fmaf(g3, wm0w, a0);
            a1 = fmaf(g0, wm1x, a1); a1 = fmaf(g1, wm1y, a1);
            a1 = fmaf(g2, wm1z, a1); a1 = fmaf(g3, wm1w, a1);
            acc[bb][0] = a0; acc[bb][1] = a1;
        }
    }
#pragma unroll
    for (int bb = 0; bb < 8; ++bb)
#pragma unroll
        for (int c = 0; c < 2; ++c) {
            float v = acc[bb][c];
            v += __shfl_xor(v, 32, 64);
            v += __shfl_xor(v, 16, 64);
            v += __shfl_xor(v,  8, 64);
            v += __shfl_xor(v,  4, 64);
            v += __shfl_xor(v,  2, 64);
            v += __shfl_xor(v,  1, 64);
            acc[bb][c] = v;
        }
    if (lane == 0)
#pragma unroll
        for (int bb = 0; bb < 8; ++bb) {
            partials[(size_t)((b0 + bb) * 2 + 0) * gridDim.x + blockIdx.x] = acc[bb][0];
            partials[(size_t)((b0 + bb) * 2 + 1) * gridDim.x + blockIdx.x] = acc[bb][1];
        }
}

// Finalize: one block per output slot (64). Slot's partials are contiguous.
__global__ __launch_bounds__(256) void finalize_kernel(
    const float4* __restrict__ partials4, const float* __restrict__ bias,
    float* __restrict__ out, int nblk4)
{
    const int j    = blockIdx.x;     // slot = b*2 + c
    const int tid  = threadIdx.x;
    const int wave = tid >> 6;
    const int lane = tid & 63;

    float s = 0.f;
    for (int k = tid; k < nblk4; k += 256) {
        const float4 v = partials4[(size_t)j * nblk4 + k];
        s += (v.x + v.y) + (v.z + v.w);
    }
    s += __shfl_xor(s, 32, 64);
    s += __shfl_xor(s, 16, 64);
    s += __shfl_xor(s,  8, 64);
    s += __shfl_xor(s,  4, 64);
    s += __shfl_xor(s,  2, 64);
    s += __shfl_xor(s,  1, 64);

    __shared__ float red[4];
    if (lane == 0) red[wave] = s;
    __syncthreads();
    if (tid == 0)
        out[j] = (red[0] + red[1]) + (red[2] + red[3]) + bias[j & 1];
}

extern "C" void kernel_launch(void* const* d_in, const int* in_sizes, int n_in,
                              void* d_out, int out_size, void* d_ws, size_t ws_size,
                              hipStream_t stream) {
    const float4* x    = (const float4*)d_in[0];
    const int4*   mask = (const int4*)d_in[1];
    const float4* w    = (const float4*)d_in[2];
    const float*  bias = (const float*)d_in[3];
    float* out = (float*)d_out;
    float* partials = (float*)d_ws;

    if (ws_size >= (size_t)NBLK3 * 64 * sizeof(float)) {
        partial_static3<<<NBLK3, TPB, 0, stream>>>(x, mask, w, partials);
        finalize_kernel<<<64, 256, 0, stream>>>((const float4*)partials, bias,
                                                out, NBLK3 / 4);
    } else {
        int nblk = (int)(ws_size / (64 * sizeof(float)));
        if (nblk < 4) nblk = 4;
        nblk &= ~3;
        partial_generic<<<nblk, 256, 0, stream>>>(x, mask, w, partials);
        finalize_kernel<<<64, 256, 0, stream>>>((const float4*)partials, bias,
                                                out, nblk / 4);
    }
}

// Round 10
// 26.488 us; speedup vs baseline: 1.0201x; 1.0201x over previous
//
#include <hip/hip_runtime.h>

#define EPS 1e-8f

// x (32,1,96,96,96) f32, mask (1,1,96,96,96) i32, weight (2,1,96,96,96) f32,
// bias (2,) f32 -> out (32,2) f32.
//
// FINAL STRUCTURE (best measured: 26.68 us, reproduced R6/R8):
//  - partial_static3: 1152 blocks x 512 thr, uniform 3 float4-steps/lane
//    (1152*64*3 == N4 exactly), 2-stage register pipeline, compiler-chosen
//    VGPR (~96). ~5.8 TB/s effective = 92% of measured 6.29 TB/s copy ceiling.
//  - finalize_kernel: 64 blocks, transposed-contiguous partials.
// Lessons encoded: R5 (VGPR cap 32 kills MLP -> 1.4 TB/s), R7 (fused
// epilogue collapses regalloc + cross-XCD fences cost 10x), R3 (coop
// grid.sync +110 us), R9 (3-deep pipeline trips occupancy cliff).
constexpr int N4    = 221184;         // 96^3 / 4 float4 elements
constexpr int TPB   = 512;            // 8 waves/block
constexpr int BPW   = 4;              // batches per wave (8*4 = 32)
constexpr int NBLK3 = 1152;           // 1152*64*3 == N4 exactly
constexpr int STR3  = NBLK3 * 64;     // 73728

struct Stage {
    int4   mi;
    float4 w0, w1;
    float4 xv[BPW];
};

__device__ __forceinline__ void load_stage(Stage& s,
        const float4* __restrict__ x, const int4* __restrict__ mask,
        const float4* __restrict__ w, int i4, int b0)
{
    s.mi = mask[i4];
    s.w0 = w[i4];
    s.w1 = w[N4 + i4];
#pragma unroll
    for (int bb = 0; bb < BPW; ++bb)
        s.xv[bb] = x[(size_t)(b0 + bb) * N4 + i4];
}

__device__ __forceinline__ void compute_stage(const Stage& s, float (&acc)[BPW][2])
{
    const float m0 = s.mi.x ? 1.f : 0.f;
    const float m1 = s.mi.y ? 1.f : 0.f;
    const float m2 = s.mi.z ? 1.f : 0.f;
    const float m3 = s.mi.w ? 1.f : 0.f;
    const float wm0x = s.w0.x * m0, wm0y = s.w0.y * m1, wm0z = s.w0.z * m2, wm0w = s.w0.w * m3;
    const float wm1x = s.w1.x * m0, wm1y = s.w1.y * m1, wm1z = s.w1.z * m2, wm1w = s.w1.w * m3;
#pragma unroll
    for (int bb = 0; bb < BPW; ++bb) {
        const float4 xv = s.xv[bb];
        const float g0 = (fabsf(xv.x) > EPS) ? xv.x : 0.f;
        const float g1 = (fabsf(xv.y) > EPS) ? xv.y : 0.f;
        const float g2 = (fabsf(xv.z) > EPS) ? xv.z : 0.f;
        const float g3 = (fabsf(xv.w) > EPS) ? xv.w : 0.f;
        float a0 = acc[bb][0], a1 = acc[bb][1];
        a0 = fmaf(g0, wm0x, a0); a0 = fmaf(g1, wm0y, a0);
        a0 = fmaf(g2, wm0z, a0); a0 = fmaf(g3, wm0w, a0);
        a1 = fmaf(g0, wm1x, a1); a1 = fmaf(g1, wm1y, a1);
        a1 = fmaf(g2, wm1z, a1); a1 = fmaf(g3, wm1w, a1);
        acc[bb][0] = a0; acc[bb][1] = a1;
    }
}

__device__ __forceinline__ void reduce_and_store(
        float (&acc)[BPW][2], int lane, int b0, int bid, int nblk,
        float* __restrict__ partials)
{
#pragma unroll
    for (int bb = 0; bb < BPW; ++bb) {
#pragma unroll
        for (int c = 0; c < 2; ++c) {
            float v = acc[bb][c];
            v += __shfl_xor(v, 32, 64);
            v += __shfl_xor(v, 16, 64);
            v += __shfl_xor(v,  8, 64);
            v += __shfl_xor(v,  4, 64);
            v += __shfl_xor(v,  2, 64);
            v += __shfl_xor(v,  1, 64);
            acc[bb][c] = v;
        }
    }
    if (lane == 0) {
#pragma unroll
        for (int bb = 0; bb < BPW; ++bb) {
            partials[(size_t)((b0 + bb) * 2 + 0) * nblk + bid] = acc[bb][0];
            partials[(size_t)((b0 + bb) * 2 + 1) * nblk + bid] = acc[bb][1];
        }
    }
}

// Hot kernel. Grid MUST be exactly NBLK3 blocks of 512 threads.
// 8 waves share the block's 64-index mask/w stream (L1-hit); wave v owns
// batches [4v,4v+4). 2-stage pipeline: 22 loads in flight at prologue,
// 11 per steady stage. NO min-waves clause, minimal epilogue.
__global__ __launch_bounds__(TPB) void partial_static3(
    const float4* __restrict__ x, const int4* __restrict__ mask,
    const float4* __restrict__ w, float* __restrict__ partials)
{
    const int tid  = threadIdx.x;
    const int wave = tid >> 6;
    const int lane = tid & 63;
    const int b0   = wave * BPW;
    const int bid  = blockIdx.x;
    const int i4   = bid * 64 + lane;          // [0, 73728)

    float acc[BPW][2];
#pragma unroll
    for (int bb = 0; bb < BPW; ++bb) { acc[bb][0] = 0.f; acc[bb][1] = 0.f; }

    Stage s0, s1;
    load_stage(s0, x, mask, w, i4,        b0);
    load_stage(s1, x, mask, w, i4 + STR3, b0);
    compute_stage(s0, acc);
    load_stage(s0, x, mask, w, i4 + 2 * STR3, b0);
    compute_stage(s1, acc);
    compute_stage(s0, acc);

    reduce_and_store(acc, lane, b0, bid, NBLK3, partials);
}

// Last-resort generic grid-stride partial (tiny ws).
__global__ __launch_bounds__(256) void partial_generic(
    const float4* __restrict__ x, const int4* __restrict__ mask,
    const float4* __restrict__ w, float* __restrict__ partials)
{
    const int tid  = threadIdx.x;
    const int wave = tid >> 6;
    const int lane = tid & 63;
    const int b0   = wave * 8;

    float acc[8][2];
#pragma unroll
    for (int bb = 0; bb < 8; ++bb) { acc[bb][0] = 0.f; acc[bb][1] = 0.f; }

    const int stride = gridDim.x * 64;
    for (int i4 = blockIdx.x * 64 + lane; i4 < N4; i4 += stride) {
        const int4   mi = mask[i4];
        const float4 w0 = w[i4];
        const float4 w1 = w[N4 + i4];
        const float m0 = mi.x ? 1.f : 0.f;
        const float m1 = mi.y ? 1.f : 0.f;
        const float m2 = mi.z ? 1.f : 0.f;
        const float m3 = mi.w ? 1.f : 0.f;
        const float wm0x = w0.x * m0, wm0y = w0.y * m1, wm0z = w0.z * m2, wm0w = w0.w * m3;
        const float wm1x = w1.x * m0, wm1y = w1.y * m1, wm1z = w1.z * m2, wm1w = w1.w * m3;
#pragma unroll
        for (int bb = 0; bb < 8; ++bb) {
            const float4 xv = x[(size_t)(b0 + bb) * N4 + i4];
            const float g0 = (fabsf(xv.x) > EPS) ? xv.x : 0.f;
            const float g1 = (fabsf(xv.y) > EPS) ? xv.y : 0.f;
            const float g2 = (fabsf(xv.z) > EPS) ? xv.z : 0.f;
            const float g3 = (fabsf(xv.w) > EPS) ? xv.w : 0.f;
            float a0 = acc[bb][0], a1 = acc[bb][1];
            a0 = fmaf(g0, wm0x, a0); a0 = fmaf(g1, wm0y, a0);
            a0 = fmaf(g2, wm0z, a0); a0 = fmaf(g3, wm0w, a0);
            a1 = fmaf(g0, wm1x, a1); a1 = fmaf(g1, wm1y, a1);
            a1 = fmaf(g2, wm1z, a1); a1 = fmaf(g3, wm1w, a1);
            acc[bb][0] = a0; acc[bb][1] = a1;
        }
    }
#pragma unroll
    for (int bb = 0; bb < 8; ++bb)
#pragma unroll
        for (int c = 0; c < 2; ++c) {
            float v = acc[bb][c];
            v += __shfl_xor(v, 32, 64);
            v += __shfl_xor(v, 16, 64);
            v += __shfl_xor(v,  8, 64);
            v += __shfl_xor(v,  4, 64);
            v += __shfl_xor(v,  2, 64);
            v += __shfl_xor(v,  1, 64);
            acc[bb][c] = v;
        }
    if (lane == 0)
#pragma unroll
        for (int bb = 0; bb < 8; ++bb) {
            partials[(size_t)((b0 + bb) * 2 + 0) * gridDim.x + blockIdx.x] = acc[bb][0];
            partials[(size_t)((b0 + bb) * 2 + 1) * gridDim.x + blockIdx.x] = acc[bb][1];
        }
}

// Finalize: one block per output slot (64). Slot's partials are contiguous.
__global__ __launch_bounds__(256) void finalize_kernel(
    const float4* __restrict__ partials4, const float* __restrict__ bias,
    float* __restrict__ out, int nblk4)
{
    const int j    = blockIdx.x;     // slot = b*2 + c
    const int tid  = threadIdx.x;
    const int wave = tid >> 6;
    const int lane = tid & 63;

    float s = 0.f;
    for (int k = tid; k < nblk4; k += 256) {
        const float4 v = partials4[(size_t)j * nblk4 + k];
        s += (v.x + v.y) + (v.z + v.w);
    }
    s += __shfl_xor(s, 32, 64);
    s += __shfl_xor(s, 16, 64);
    s += __shfl_xor(s,  8, 64);
    s += __shfl_xor(s,  4, 64);
    s += __shfl_xor(s,  2, 64);
    s += __shfl_xor(s,  1, 64);

    __shared__ float red[4];
    if (lane == 0) red[wave] = s;
    __syncthreads();
    if (tid == 0)
        out[j] = (red[0] + red[1]) + (red[2] + red[3]) + bias[j & 1];
}

extern "C" void kernel_launch(void* const* d_in, const int* in_sizes, int n_in,
                              void* d_out, int out_size, void* d_ws, size_t ws_size,
                              hipStream_t stream) {
    const float4* x    = (const float4*)d_in[0];
    const int4*   mask = (const int4*)d_in[1];
    const float4* w    = (const float4*)d_in[2];
    const float*  bias = (const float*)d_in[3];
    float* out = (float*)d_out;
    float* partials = (float*)d_ws;

    if (ws_size >= (size_t)NBLK3 * 64 * sizeof(float)) {
        partial_static3<<<NBLK3, TPB, 0, stream>>>(x, mask, w, partials);
        finalize_kernel<<<64, 256, 0, stream>>>((const float4*)partials, bias,
                                                out, NBLK3 / 4);
    } else {
        int nblk = (int)(ws_size / (64 * sizeof(float)));
        if (nblk < 4) nblk = 4;
        nblk &= ~3;
        partial_generic<<<nblk, 256, 0, stream>>>(x, mask, w, partials);
        finalize_kernel<<<64, 256, 0, stream>>>((const float4*)partials, bias,
                                                out, nblk / 4);
    }
}